// Round 7
// baseline (195.337 us; speedup 1.0000x reference)
//
#include <hip/hip_runtime.h>
#include <hip/hip_bf16.h>

// Problem: B=8, T=256, V=32, D=256.
// Per-v GEMM: M=N=2048 (rows = i*T+q / j*T+k), K=256, then exp + 3 reductions.
// feature[B,T,V,D]: element (row, v, d) at feat[(row*32 + v)*256 + d].
// v7 = v5b/v6 main + T15 acc double-pipeline:
//  - Two accumulator sets (accA/accB, named -> static indexing, rule #20).
//    Iteration n issues MFMA into cur WITHOUT waiting, then runs the exp
//    epilogue of tile n-1 from prev -> matrix pipe and VALU/trans pipe
//    overlap inside each wave. Epilogue de-serialized off the MFMA path.
//  - Counted-vmcnt pipeline unchanged from v5b (proven): s_barrier +
//    s_waitcnt vmcnt(4) (never 0 mid-loop), stage tile n+2 after ds_reads.
//  - Repack unchanged from v6 (two patterns measured identical -> externally
//    BW-gated; lever exhausted).

typedef __attribute__((ext_vector_type(4))) float f32x4;
typedef __attribute__((ext_vector_type(4))) int   i32x4;
typedef __attribute__((ext_vector_type(8))) int   i32x8;
typedef __attribute__((ext_vector_type(8))) __bf16 bf16x8;   // fallback path

#if __has_builtin(__builtin_amdgcn_exp2f)
#define EXP2(x) __builtin_amdgcn_exp2f(x)
#else
#define EXP2(x) exp2f(x)
#endif

#define WAIT_VMCNT(N)                                              \
    do {                                                           \
        asm volatile("s_waitcnt vmcnt(" #N ")" ::: "memory");      \
        __builtin_amdgcn_sched_barrier(0);                         \
    } while (0)
#define WAIT_LGKM0                                                 \
    do {                                                           \
        asm volatile("s_waitcnt lgkmcnt(0)" ::: "memory");         \
        __builtin_amdgcn_sched_barrier(0);                         \
    } while (0)
#define BARRIER()                                                  \
    do {                                                           \
        __builtin_amdgcn_s_barrier();                              \
        __builtin_amdgcn_sched_barrier(0);                         \
    } while (0)

__device__ __forceinline__ unsigned short f2bf(float f) {
    unsigned u = __builtin_bit_cast(unsigned, f);
    u += 0x7FFFu + ((u >> 16) & 1u);   // RNE (no NaNs in data)
    return (unsigned short)(u >> 16);
}

template <bool HI>
__device__ __forceinline__ unsigned cvt2fp8(float a, float b, unsigned old) {
    return __builtin_amdgcn_cvt_pk_fp8_f32(a, b, old, HI);
}
__device__ __forceinline__ unsigned pack4fp8(float x, float y, float z, float w) {
    return cvt2fp8<true>(z, w, cvt2fp8<false>(x, y, 0u));
}

__device__ __forceinline__ void async16(const void* g, void* l) {
    __builtin_amdgcn_global_load_lds(
        (const __attribute__((address_space(1))) unsigned int*)g,
        (__attribute__((address_space(3))) unsigned int*)l,
        16, 0, 0);
}

__device__ __forceinline__ i32x8 cat8(i32x4 lo, i32x4 hi) {
    i32x8 r;
    r[0] = lo[0]; r[1] = lo[1]; r[2] = lo[2]; r[3] = lo[3];
    r[4] = hi[0]; r[5] = hi[1]; r[6] = hi[2]; r[7] = hi[3];
    return r;
}

// DPP row-sum over 16-lane rows; full sum lands in lane 15 of each row.
template <int CTRL>
__device__ __forceinline__ float dpp_add(float x) {
    int y = __builtin_amdgcn_update_dpp(0, __builtin_bit_cast(int, x),
                                        CTRL, 0xf, 0xf, true);
    return x + __builtin_bit_cast(float, y);
}
__device__ __forceinline__ float rowsum16(float x) {
    x = dpp_add<0x111>(x);   // row_shr:1
    x = dpp_add<0x112>(x);   // row_shr:2
    x = dpp_add<0x114>(x);   // row_shr:4
    x = dpp_add<0x118>(x);   // row_shr:8
    return x;
}

// ------------- repack: streaming fp32 -> fp8 e4m3 (plain layout) -------------
// grid (2048, 2): y = tensor. Lane-contiguous float4 loads + dword stores,
// grid-stride x8. Block (0,0) also zeroes the 3*2048 counter floats.
__global__ __launch_bounds__(256) void infonce_repack_fp8(
    const float* __restrict__ feat, const float* __restrict__ feat_aug,
    unsigned char* __restrict__ pA, unsigned char* __restrict__ pB,
    float* __restrict__ counters)
{
    const int tid = threadIdx.x;
    if (blockIdx.x == 0 && blockIdx.y == 0) {
        #pragma unroll
        for (int k = 0; k < 24; ++k) counters[k * 256 + tid] = 0.f;
    }
    const bool isA = (blockIdx.y == 0);
    const float sc = isA ? 1.4426950408889634f : 1.0f;
    const float* src = isA ? feat : feat_aug;
    unsigned char* dst = isA ? pA : pB;
    const unsigned g = blockIdx.x * 256u + (unsigned)tid;   // float4 lane slot
    #pragma unroll
    for (int it = 0; it < 8; ++it) {
        const unsigned idx = it * 524288u + g;              // float4 index
        const float4 f = *(const float4*)(src + (size_t)idx * 4);
        const unsigned p = pack4fp8(f.x * sc, f.y * sc, f.z * sc, f.w * sc);
        *(unsigned*)(dst + (size_t)idx * 4) = p;            // byte i = float i
    }
}

// ----- main: N-sweep MX-fp8 GEMM + exp + reductions, counted-vmcnt pipeline --
// block = (tileM 0..15, v 0..31). A: [128 rows][16 groups x 16B] in LDS once,
// frags hoisted to regs. B: 2 x [64 rows][256 B] double buffer. 64 KB LDS.
// T15: MFMA(tile n) issues into cur acc; exp-epilogue(tile n-1) runs from the
// other acc set with NO wait on the in-flight MFMAs (separate pipes overlap).
__global__ __launch_bounds__(256, 2) void infonce_main_nl(
    const unsigned char* __restrict__ pA, const unsigned char* __restrict__ pB,
    float* __restrict__ total, float* __restrict__ selfp, float* __restrict__ ap)
{
    __shared__ __align__(16) unsigned char As[128 * 256];
    __shared__ __align__(16) unsigned char Bs[2][64 * 256];
    // scratch aliases As after the final loop barrier (A frags live in regs)
    float (*ls_row2)[128]  = (float (*)[128])(void*)As;
    float (*ls_self2)[128] = (float (*)[128])(void*)(As + 1024);

    const int tid  = threadIdx.x;
    const int lane = tid & 63;
    const int w    = tid >> 6;        // wave 0..3
    const int wm   = w >> 1;          // A rows half
    const int wn   = w & 1;           // B cols half (within 64-col tile)
    const int lrow = lane & 15;
    const int quad = lane >> 4;

    const int tileM = blockIdx.x;     // 0..15
    const int v     = blockIdx.y;     // 0..31
    const int nD0   = (tileM >> 1) * 4;   // first diagonal n-iter

    const size_t vOff = (size_t)v * 256;

    // ---- stage A (128 rows x 256 B), swizzled, once ----
    {
        const size_t rowM = (size_t)(tileM * 128 + w * 32 + quad) * 8192 + vOff;
        #pragma unroll
        for (int i = 0; i < 8; ++i) {
            const int lg = (lrow ^ ((i * 4 + quad) & 15)) << 4;
            async16(pA + rowM + (size_t)i * 4 * 8192 + lg, &As[(w * 32 + i * 4) * 256]);
        }
    }
    // ---- stage B tiles 0 and 1 (pipeline depth 2) ----
    const size_t rowNbase = (size_t)(w * 16 + quad) * 8192 + vOff;
    #pragma unroll
    for (int nn = 0; nn < 2; ++nn) {
        const unsigned char* srcB = pB + rowNbase + (size_t)nn * 64 * 8192;
        #pragma unroll
        for (int i = 0; i < 4; ++i) {
            const int lg = (lrow ^ ((i * 4 + quad) & 15)) << 4;
            async16(srcB + (size_t)i * 4 * 8192 + lg,
                    &Bs[nn][(w * 16 + i * 4) * 256]);
        }
    }
    // A(8)+B0(4) landed; B1(4) may still fly.
    WAIT_VMCNT(4);
    BARRIER();

    // ---- hoist A fragments to registers (LDS read once) ----
    i32x8 af[2][4];   // [k-half][m-tile]
    #pragma unroll
    for (int h = 0; h < 2; ++h)
        #pragma unroll
        for (int t = 0; t < 4; ++t) {
            const int rA = (wm * 64 + t * 16 + lrow) * 256;
            const int g0 = ((h * 8 + quad * 2) ^ lrow) * 16;
            af[h][t] = cat8(*(const i32x4*)&As[rA + g0],
                            *(const i32x4*)&As[rA + (g0 ^ 16)]);
        }

    float rowp[4][4];   // row partials, all n
    float selfr[4][4];  // row partials, diagonal n only
    #pragma unroll
    for (int t = 0; t < 4; ++t)
        #pragma unroll
        for (int r = 0; r < 4; ++r) { rowp[t][r] = 0.f; selfr[t][r] = 0.f; }

    f32x4 accA[4][2], accB[4][2];   // two named acc sets (static indexing)

    // ---- exp epilogue for the tile held in `prev` (tile index m) ----
    auto epilogue = [&](const int m, f32x4 (&prev)[4][2]) {
        const bool diagIter = (m >= nD0) && (m < nD0 + 4);
        float colp0 = 0.f, colp1 = 0.f;
        #pragma unroll
        for (int t = 0; t < 4; ++t)
            #pragma unroll
            for (int r = 0; r < 4; ++r) {
                float e0 = EXP2(prev[t][0][r]);
                float e1 = EXP2(prev[t][1][r]);
                rowp[t][r] += e0 + e1;
                if (diagIter) { selfr[t][r] += e0 + e1; colp0 += e0; colp1 += e1; }
            }
        if (diagIter) {   // col sums -> ap (wave-uniform branch, 4 of 32 iters)
            float q0 = colp0, q1 = colp1;
            q0 += __shfl_xor(q0, 16); q0 += __shfl_xor(q0, 32);
            q1 += __shfl_xor(q1, 16); q1 += __shfl_xor(q1, 32);
            if (lane < 16) {
                atomicAdd(&ap[m * 64 + wn * 32 + lane], q0);
                atomicAdd(&ap[m * 64 + wn * 32 + 16 + lane], q1);
            }
        }
    };

    // ---- one pipeline step: MFMA tile n into cur, epilogue tile n-1 ----
    auto step = [&](const int n, f32x4 (&cur)[4][2], f32x4 (&prev)[4][2]) {
        const int b = n & 1;
        if (n == 31) { WAIT_VMCNT(0); } else { WAIT_VMCNT(4); }
        BARRIER();                      // all waves: Bs[b] contents valid

        // ---- read ALL B fragments of this tile (8 x ds_read_b128) ----
        i32x8 bfr[2][2];                // [k-half][tj]
        #pragma unroll
        for (int h = 0; h < 2; ++h)
            #pragma unroll
            for (int tj = 0; tj < 2; ++tj) {
                const int rB = (wn * 32 + tj * 16 + lrow) * 256;
                const int g0 = ((h * 8 + quad * 2) ^ lrow) * 16;
                bfr[h][tj] = cat8(*(const i32x4*)&Bs[b][rB + g0],
                                  *(const i32x4*)&Bs[b][rB + (g0 ^ 16)]);
            }
        WAIT_LGKM0;                     // my reads of Bs[b] complete
        BARRIER();                      // everyone's reads done -> overwritable

        if (n < 30) {                   // stage tile n+2 into Bs[b]
            const unsigned char* src = pB + rowNbase + (size_t)(n + 2) * 64 * 8192;
            #pragma unroll
            for (int i = 0; i < 4; ++i) {
                const int lg = (lrow ^ ((i * 4 + quad) & 15)) << 4;
                async16(src + (size_t)i * 4 * 8192 + lg,
                        &Bs[b][(w * 16 + i * 4) * 256]);
            }
        }

        // ---- MFMA tile n -> cur (no wait on results) ----
        #pragma unroll
        for (int t = 0; t < 4; ++t)
            #pragma unroll
            for (int tj = 0; tj < 2; ++tj)
                cur[t][tj] = (f32x4){0.f, 0.f, 0.f, 0.f};
        __builtin_amdgcn_s_setprio(1);
        #pragma unroll
        for (int h = 0; h < 2; ++h)
            #pragma unroll
            for (int ti = 0; ti < 4; ++ti)
                #pragma unroll
                for (int tj = 0; tj < 2; ++tj)
                    cur[ti][tj] = __builtin_amdgcn_mfma_scale_f32_16x16x128_f8f6f4(
                        af[h][ti], bfr[h][tj], cur[ti][tj],
                        0, 0, 0, 127, 0, 127);   // fp8/fp8, unit E8M0 scales
        __builtin_amdgcn_s_setprio(0);

        // ---- epilogue of tile n-1 overlaps the in-flight MFMAs ----
        if (n > 0) epilogue(n - 1, prev);
        // no per-iter vmcnt drain: next step's WAIT_VMCNT is the only gate
    };

    #pragma unroll 1
    for (int hlf = 0; hlf < 16; ++hlf) {    // 2 tiles per trip, static acc swap
        step(2 * hlf,     accA, accB);
        step(2 * hlf + 1, accB, accA);
    }
    epilogue(31, accB);                     // drain: last tile's epilogue

    // ---- final row reductions: DPP over the 16 cols held per lane-row ----
    #pragma unroll
    for (int t = 0; t < 4; ++t)
        #pragma unroll
        for (int r = 0; r < 4; ++r) {
            float rs = rowsum16(rowp[t][r]);
            float ss = rowsum16(selfr[t][r]);
            if (lrow == 15) {
                const int idx = wm * 64 + t * 16 + quad * 4 + r;
                ls_row2[wn][idx]  = rs;
                ls_self2[wn][idx] = ss;
            }
        }
    __syncthreads();
    if (tid < 128) {
        atomicAdd(&total[tileM * 128 + tid], ls_row2[0][tid] + ls_row2[1][tid]);
    } else {
        const int t2 = tid - 128;
        atomicAdd(&selfp[tileM * 128 + t2], ls_self2[0][t2] + ls_self2[1][t2]);
    }
}

// ---------------- fallback main (round-1 kernel, fp32 staging) ---------------
__global__ __launch_bounds__(256) void infonce_main_slow(
    const float* __restrict__ feat, const float* __restrict__ feat_aug,
    float* __restrict__ total, float* __restrict__ selfp, float* __restrict__ ap)
{
    __shared__ __align__(16) unsigned short As[128][72];
    __shared__ __align__(16) unsigned short Bs[128][72];
    __shared__ float ls_row[128];
    __shared__ float ls_col[128];

    const int tid  = threadIdx.x;
    const int lane = tid & 63;
    const int w    = tid >> 6;
    const int wm   = w >> 1;
    const int wn   = w & 1;
    const int lrow = lane & 15;
    const int quad = lane >> 4;

    const int tileM = blockIdx.x & 15;
    const int tileN = blockIdx.x >> 4;
    const int v     = blockIdx.y;
    const bool diag = (tileM >> 1) == (tileN >> 1);

    if (tid < 128) ls_row[tid] = 0.0f;
    else           ls_col[tid - 128] = 0.0f;

    const float* aBase = feat     + (size_t)v * 256;
    const float* bBase = feat_aug + (size_t)v * 256;

    f32x4 acc[4][4];
    #pragma unroll
    for (int i = 0; i < 4; ++i)
        #pragma unroll
        for (int j = 0; j < 4; ++j)
            acc[i][j] = (f32x4){0.f, 0.f, 0.f, 0.f};

    const int srow = tid >> 4;
    const int scol = (tid & 15) * 4;

    for (int s = 0; s < 4; ++s) {
        const int k0 = s * 64;
        if (s) __syncthreads();
        #pragma unroll
        for (int it = 0; it < 8; ++it) {
            const int row = it * 16 + srow;
            const float4 a4 = *(const float4*)(aBase + (size_t)(tileM * 128 + row) * 8192 + k0 + scol);
            const float4 b4 = *(const float4*)(bBase + (size_t)(tileN * 128 + row) * 8192 + k0 + scol);
            uint2 wa, wb;
            wa.x = (unsigned)f2bf(a4.x) | ((unsigned)f2bf(a4.y) << 16);
            wa.y = (unsigned)f2bf(a4.z) | ((unsigned)f2bf(a4.w) << 16);
            wb.x = (unsigned)f2bf(b4.x) | ((unsigned)f2bf(b4.y) << 16);
            wb.y = (unsigned)f2bf(b4.z) | ((unsigned)f2bf(b4.w) << 16);
            *(uint2*)&As[row][scol] = wa;
            *(uint2*)&Bs[row][scol] = wb;
        }
        __syncthreads();
        #pragma unroll
        for (int kk = 0; kk < 64; kk += 32) {
            bf16x8 af[4], bfr[4];
            #pragma unroll
            for (int t = 0; t < 4; ++t) {
                af[t]  = *(const bf16x8*)&As[wm * 64 + t * 16 + lrow][kk + quad * 8];
                bfr[t] = *(const bf16x8*)&Bs[wn * 64 + t * 16 + lrow][kk + quad * 8];
            }
            #pragma unroll
            for (int ti = 0; ti < 4; ++ti)
                #pragma unroll
                for (int tj = 0; tj < 4; ++tj)
                    acc[ti][tj] = __builtin_amdgcn_mfma_f32_16x16x32_bf16(
                        af[ti], bfr[tj], acc[ti][tj], 0, 0, 0);
        }
    }

    float colp[4] = {0.f, 0.f, 0.f, 0.f};
    #pragma unroll
    for (int ti = 0; ti < 4; ++ti) {
        #pragma unroll
        for (int r = 0; r < 4; ++r) {
            float e0 = __expf(acc[ti][0][r]);
            float e1 = __expf(acc[ti][1][r]);
            float e2 = __expf(acc[ti][2][r]);
            float e3 = __expf(acc[ti][3][r]);
            colp[0] += e0; colp[1] += e1; colp[2] += e2; colp[3] += e3;
            float rp = (e0 + e1) + (e2 + e3);
            rp += __shfl_xor(rp, 1);
            rp += __shfl_xor(rp, 2);
            rp += __shfl_xor(rp, 4);
            rp += __shfl_xor(rp, 8);
            if (lrow == 0)
                atomicAdd(&ls_row[wm * 64 + ti * 16 + quad * 4 + r], rp);
        }
    }
    if (diag) {
        #pragma unroll
        for (int tj = 0; tj < 4; ++tj) {
            float q = colp[tj];
            q += __shfl_xor(q, 16);
            q += __shfl_xor(q, 32);
            if (lane < 16)
                atomicAdd(&ls_col[wn * 64 + tj * 16 + lane], q);
        }
    }
    __syncthreads();
    if (tid < 128) {
        const float rs = ls_row[tid];
        const int rowg = tileM * 128 + tid;
        atomicAdd(&total[rowg], rs);
        if (diag) atomicAdd(&selfp[rowg], rs);
    } else if (diag) {
        const int t2 = tid - 128;
        atomicAdd(&ap[tileN * 128 + t2], ls_col[t2]);
    }
}

__global__ __launch_bounds__(256) void infonce_finalize(
    const float* __restrict__ total, const float* __restrict__ selfp,
    const float* __restrict__ ap, float* __restrict__ out)
{
    __shared__ float red[4];
    const int tid = threadIdx.x;
    float s = 0.f;
    for (int e = tid; e < 2048; e += 256) {
        const float an = total[e] - selfp[e];
        s += logf(an / ap[e]);
    }
    #pragma unroll
    for (int m = 32; m >= 1; m >>= 1) s += __shfl_xor(s, m);
    if ((tid & 63) == 0) red[tid >> 6] = s;
    __syncthreads();
    if (tid == 0) out[0] = (red[0] + red[1] + red[2] + red[3]) * (1.0f / 256.0f);
}

extern "C" void kernel_launch(void* const* d_in, const int* in_sizes, int n_in,
                              void* d_out, int out_size, void* d_ws, size_t ws_size,
                              hipStream_t stream) {
    const float* feat     = (const float*)d_in[0];
    const float* feat_aug = (const float*)d_in[1];
    float* total = (float*)d_ws;
    float* selfp = total + 2048;
    float* ap    = selfp + 2048;

    const size_t packBytes = (size_t)2048 * 8192;                  // per tensor, fp8
    const size_t need = 32768 + 2 * packBytes;
    if (ws_size >= need) {
        unsigned char* pA = (unsigned char*)d_ws + 32768;
        unsigned char* pB = pA + packBytes;
        infonce_repack_fp8<<<dim3(2048, 2), 256, 0, stream>>>(feat, feat_aug, pA, pB, total);
        infonce_main_nl<<<dim3(16, 32), 256, 0, stream>>>(pA, pB, total, selfp, ap);
    } else {
        (void)hipMemsetAsync(d_ws, 0, 3 * 2048 * sizeof(float), stream);
        infonce_main_slow<<<dim3(256, 32), 256, 0, stream>>>(feat, feat_aug, total, selfp, ap);
    }
    infonce_finalize<<<1, 256, 0, stream>>>(total, selfp, ap, (float*)d_out);
}

// Round 8
// 189.401 us; speedup vs baseline: 1.0313x; 1.0313x over previous
//
#include <hip/hip_runtime.h>
#include <hip/hip_bf16.h>

// Problem: B=8, T=256, V=32, D=256.
// Per-v GEMM: M=N=2048 (rows = i*T+q / j*T+k), K=256, then exp + 3 reductions.
// feature[B,T,V,D]: element (row, v, d) at feat[(row*32 + v)*256 + d].
// v8 = v5b main (T15 reverted: 185->195 regression) + T1 XCD v-grouping:
//  - Diagnosis: main re-reads its v's 512 KB B panel 16x across tileM blocks
//    -> 268 MB of L3 traffic in ~42 us = ~6.8 TB/s, pinned at the L3/HBM
//    streaming ceiling (MfmaUtil 26% because memory-starved, not pipe-bound).
//    Repack is separately AT roofline (320 MB @ 5.9 TB/s) - lever exhausted.
//  - Fix: decode (tileM, v) from linear block id so all 16 tileM blocks of a
//    v land on ONE XCD (id%8 -> XCD round-robin): per-XCD working set =
//    4v x 512KB B + 2MB A = 4MB = L2 size; 16x B reuse served from L2
//    (34.5 TB/s) instead of L3. Wrong-mapping risk: degrades to an arbitrary
//    bijection, correctness unaffected.
//  - Counted-vmcnt pipeline unchanged from v5b (proven).

typedef __attribute__((ext_vector_type(4))) float f32x4;
typedef __attribute__((ext_vector_type(4))) int   i32x4;
typedef __attribute__((ext_vector_type(8))) int   i32x8;
typedef __attribute__((ext_vector_type(8))) __bf16 bf16x8;   // fallback path

#if __has_builtin(__builtin_amdgcn_exp2f)
#define EXP2(x) __builtin_amdgcn_exp2f(x)
#else
#define EXP2(x) exp2f(x)
#endif

#define WAIT_VMCNT(N)                                              \
    do {                                                           \
        asm volatile("s_waitcnt vmcnt(" #N ")" ::: "memory");      \
        __builtin_amdgcn_sched_barrier(0);                         \
    } while (0)
#define WAIT_LGKM0                                                 \
    do {                                                           \
        asm volatile("s_waitcnt lgkmcnt(0)" ::: "memory");         \
        __builtin_amdgcn_sched_barrier(0);                         \
    } while (0)
#define BARRIER()                                                  \
    do {                                                           \
        __builtin_amdgcn_s_barrier();                              \
        __builtin_amdgcn_sched_barrier(0);                         \
    } while (0)

__device__ __forceinline__ unsigned short f2bf(float f) {
    unsigned u = __builtin_bit_cast(unsigned, f);
    u += 0x7FFFu + ((u >> 16) & 1u);   // RNE (no NaNs in data)
    return (unsigned short)(u >> 16);
}

template <bool HI>
__device__ __forceinline__ unsigned cvt2fp8(float a, float b, unsigned old) {
    return __builtin_amdgcn_cvt_pk_fp8_f32(a, b, old, HI);
}
__device__ __forceinline__ unsigned pack4fp8(float x, float y, float z, float w) {
    return cvt2fp8<true>(z, w, cvt2fp8<false>(x, y, 0u));
}

__device__ __forceinline__ void async16(const void* g, void* l) {
    __builtin_amdgcn_global_load_lds(
        (const __attribute__((address_space(1))) unsigned int*)g,
        (__attribute__((address_space(3))) unsigned int*)l,
        16, 0, 0);
}

__device__ __forceinline__ i32x8 cat8(i32x4 lo, i32x4 hi) {
    i32x8 r;
    r[0] = lo[0]; r[1] = lo[1]; r[2] = lo[2]; r[3] = lo[3];
    r[4] = hi[0]; r[5] = hi[1]; r[6] = hi[2]; r[7] = hi[3];
    return r;
}

// DPP row-sum over 16-lane rows; full sum lands in lane 15 of each row.
template <int CTRL>
__device__ __forceinline__ float dpp_add(float x) {
    int y = __builtin_amdgcn_update_dpp(0, __builtin_bit_cast(int, x),
                                        CTRL, 0xf, 0xf, true);
    return x + __builtin_bit_cast(float, y);
}
__device__ __forceinline__ float rowsum16(float x) {
    x = dpp_add<0x111>(x);   // row_shr:1
    x = dpp_add<0x112>(x);   // row_shr:2
    x = dpp_add<0x114>(x);   // row_shr:4
    x = dpp_add<0x118>(x);   // row_shr:8
    return x;
}

// ------------- repack: streaming fp32 -> fp8 e4m3 (plain layout) -------------
// grid (2048, 2): y = tensor. Lane-contiguous float4 loads + dword stores,
// grid-stride x8. Block (0,0) also zeroes the 3*2048 counter floats.
// AT ROOFLINE: 320 MB combined traffic @ ~5.9 TB/s (94% of 6.3 ceiling).
__global__ __launch_bounds__(256) void infonce_repack_fp8(
    const float* __restrict__ feat, const float* __restrict__ feat_aug,
    unsigned char* __restrict__ pA, unsigned char* __restrict__ pB,
    float* __restrict__ counters)
{
    const int tid = threadIdx.x;
    if (blockIdx.x == 0 && blockIdx.y == 0) {
        #pragma unroll
        for (int k = 0; k < 24; ++k) counters[k * 256 + tid] = 0.f;
    }
    const bool isA = (blockIdx.y == 0);
    const float sc = isA ? 1.4426950408889634f : 1.0f;
    const float* src = isA ? feat : feat_aug;
    unsigned char* dst = isA ? pA : pB;
    const unsigned g = blockIdx.x * 256u + (unsigned)tid;   // float4 lane slot
    #pragma unroll
    for (int it = 0; it < 8; ++it) {
        const unsigned idx = it * 524288u + g;              // float4 index
        const float4 f = *(const float4*)(src + (size_t)idx * 4);
        const unsigned p = pack4fp8(f.x * sc, f.y * sc, f.z * sc, f.w * sc);
        *(unsigned*)(dst + (size_t)idx * 4) = p;            // byte i = float i
    }
}

// ----- main: N-sweep MX-fp8 GEMM + exp + reductions, counted-vmcnt pipeline --
// 512 blocks; (tileM, v) decoded XCD-aware (see header). A: [128 rows][16
// groups x 16B] in LDS once, frags hoisted to regs. B: 2 x [64 rows][256 B]
// double buffer. 64 KB LDS, 2 blocks/CU.
__global__ __launch_bounds__(256, 2) void infonce_main_nl(
    const unsigned char* __restrict__ pA, const unsigned char* __restrict__ pB,
    float* __restrict__ total, float* __restrict__ selfp, float* __restrict__ ap)
{
    __shared__ __align__(16) unsigned char As[128 * 256];
    __shared__ __align__(16) unsigned char Bs[2][64 * 256];
    // scratch aliases As after the final loop barrier (A frags live in regs)
    float (*ls_row2)[128]  = (float (*)[128])(void*)As;
    float (*ls_self2)[128] = (float (*)[128])(void*)(As + 1024);

    const int tid  = threadIdx.x;
    const int lane = tid & 63;
    const int w    = tid >> 6;        // wave 0..3
    const int wm   = w >> 1;          // A rows half
    const int wn   = w & 1;           // B cols half (within 64-col tile)
    const int lrow = lane & 15;
    const int quad = lane >> 4;

    // ---- T1: XCD-aware (tileM, v) decode ----
    // Round-robin dispatch puts linear id l on XCD l%8. Give XCD k the 16
    // tileM-blocks of v in [4k, 4k+4): per-XCD B+A working set ~4MB = L2.
    const int lin   = blockIdx.x + 16 * blockIdx.y;   // 0..511
    const int xcd   = lin & 7;
    const int slot  = lin >> 3;                       // 0..63
    const int tileM = slot & 15;                      // 0..15
    const int v     = 4 * xcd + (slot >> 4);          // 0..31
    const int nD0   = (tileM >> 1) * 4;   // first diagonal n-iter

    const size_t vOff = (size_t)v * 256;

    // ---- stage A (128 rows x 256 B), swizzled, once ----
    {
        const size_t rowM = (size_t)(tileM * 128 + w * 32 + quad) * 8192 + vOff;
        #pragma unroll
        for (int i = 0; i < 8; ++i) {
            const int lg = (lrow ^ ((i * 4 + quad) & 15)) << 4;
            async16(pA + rowM + (size_t)i * 4 * 8192 + lg, &As[(w * 32 + i * 4) * 256]);
        }
    }
    // ---- stage B tiles 0 and 1 (pipeline depth 2) ----
    const size_t rowNbase = (size_t)(w * 16 + quad) * 8192 + vOff;
    #pragma unroll
    for (int nn = 0; nn < 2; ++nn) {
        const unsigned char* srcB = pB + rowNbase + (size_t)nn * 64 * 8192;
        #pragma unroll
        for (int i = 0; i < 4; ++i) {
            const int lg = (lrow ^ ((i * 4 + quad) & 15)) << 4;
            async16(srcB + (size_t)i * 4 * 8192 + lg,
                    &Bs[nn][(w * 16 + i * 4) * 256]);
        }
    }
    // A(8)+B0(4) landed; B1(4) may still fly.
    WAIT_VMCNT(4);
    BARRIER();

    // ---- hoist A fragments to registers (LDS read once) ----
    i32x8 af[2][4];   // [k-half][m-tile]
    #pragma unroll
    for (int h = 0; h < 2; ++h)
        #pragma unroll
        for (int t = 0; t < 4; ++t) {
            const int rA = (wm * 64 + t * 16 + lrow) * 256;
            const int g0 = ((h * 8 + quad * 2) ^ lrow) * 16;
            af[h][t] = cat8(*(const i32x4*)&As[rA + g0],
                            *(const i32x4*)&As[rA + (g0 ^ 16)]);
        }

    float rowp[4][4];   // row partials, all n
    float selfr[4][4];  // row partials, diagonal n only
    #pragma unroll
    for (int t = 0; t < 4; ++t)
        #pragma unroll
        for (int r = 0; r < 4; ++r) { rowp[t][r] = 0.f; selfr[t][r] = 0.f; }

    // Per-iteration body AFTER the vmcnt gate. Block-uniform branches only.
    auto iterBody = [&](const int n) {
        const int b = n & 1;
        BARRIER();                      // all waves: Bs[b] contents valid

        // ---- read ALL B fragments of this tile (8 x ds_read_b128) ----
        i32x8 bfr[2][2];                // [k-half][tj]
        #pragma unroll
        for (int h = 0; h < 2; ++h)
            #pragma unroll
            for (int tj = 0; tj < 2; ++tj) {
                const int rB = (wn * 32 + tj * 16 + lrow) * 256;
                const int g0 = ((h * 8 + quad * 2) ^ lrow) * 16;
                bfr[h][tj] = cat8(*(const i32x4*)&Bs[b][rB + g0],
                                  *(const i32x4*)&Bs[b][rB + (g0 ^ 16)]);
            }
        WAIT_LGKM0;                     // my reads of Bs[b] complete
        BARRIER();                      // everyone's reads done -> overwritable

        if (n < 30) {                   // stage tile n+2 into Bs[b]
            const unsigned char* src = pB + rowNbase + (size_t)(n + 2) * 64 * 8192;
            #pragma unroll
            for (int i = 0; i < 4; ++i) {
                const int lg = (lrow ^ ((i * 4 + quad) & 15)) << 4;
                async16(src + (size_t)i * 4 * 8192 + lg,
                        &Bs[b][(w * 16 + i * 4) * 256]);
            }
        }

        // ---- MFMA (regs only) ----
        f32x4 acc[4][2];
        #pragma unroll
        for (int t = 0; t < 4; ++t)
            #pragma unroll
            for (int tj = 0; tj < 2; ++tj)
                acc[t][tj] = (f32x4){0.f, 0.f, 0.f, 0.f};
        __builtin_amdgcn_s_setprio(1);
        #pragma unroll
        for (int h = 0; h < 2; ++h)
            #pragma unroll
            for (int ti = 0; ti < 4; ++ti)
                #pragma unroll
                for (int tj = 0; tj < 2; ++tj)
                    acc[ti][tj] = __builtin_amdgcn_mfma_scale_f32_16x16x128_f8f6f4(
                        af[h][ti], bfr[h][tj], acc[ti][tj],
                        0, 0, 0, 127, 0, 127);   // fp8/fp8, unit E8M0 scales
        __builtin_amdgcn_s_setprio(0);

        // ---- epilogue-accumulate: E = exp2(acc) (A prescaled by log2 e) ----
        const bool diagIter = (n >= nD0) && (n < nD0 + 4);
        float colp0 = 0.f, colp1 = 0.f;
        #pragma unroll
        for (int t = 0; t < 4; ++t)
            #pragma unroll
            for (int r = 0; r < 4; ++r) {
                float e0 = EXP2(acc[t][0][r]);
                float e1 = EXP2(acc[t][1][r]);
                rowp[t][r] += e0 + e1;
                if (diagIter) { selfr[t][r] += e0 + e1; colp0 += e0; colp1 += e1; }
            }
        if (diagIter) {   // col sums -> ap (wave-uniform branch, 4 of 32 iters)
            float q0 = colp0, q1 = colp1;
            q0 += __shfl_xor(q0, 16); q0 += __shfl_xor(q0, 32);
            q1 += __shfl_xor(q1, 16); q1 += __shfl_xor(q1, 32);
            if (lane < 16) {
                atomicAdd(&ap[n * 64 + wn * 32 + lane], q0);
                atomicAdd(&ap[n * 64 + wn * 32 + 16 + lane], q1);
            }
        }
        // no per-iter vmcnt drain: next iter's WAIT_VMCNT is the only gate
    };

    for (int n = 0; n < 31; ++n) {
        // tile n staged 2 iters ago: only the newest 4 loads (tile n+1) may
        // remain outstanding. (Diag-iter atomics only add harmless waiting.)
        WAIT_VMCNT(4);
        iterBody(n);
    }
    WAIT_VMCNT(0);       // last tile: drain everything
    iterBody(31);

    // ---- final row reductions: DPP over the 16 cols held per lane-row ----
    #pragma unroll
    for (int t = 0; t < 4; ++t)
        #pragma unroll
        for (int r = 0; r < 4; ++r) {
            float rs = rowsum16(rowp[t][r]);
            float ss = rowsum16(selfr[t][r]);
            if (lrow == 15) {
                const int idx = wm * 64 + t * 16 + quad * 4 + r;
                ls_row2[wn][idx]  = rs;
                ls_self2[wn][idx] = ss;
            }
        }
    __syncthreads();
    if (tid < 128) {
        atomicAdd(&total[tileM * 128 + tid], ls_row2[0][tid] + ls_row2[1][tid]);
    } else {
        const int t2 = tid - 128;
        atomicAdd(&selfp[tileM * 128 + t2], ls_self2[0][t2] + ls_self2[1][t2]);
    }
}

// ---------------- fallback main (round-1 kernel, fp32 staging) ---------------
__global__ __launch_bounds__(256) void infonce_main_slow(
    const float* __restrict__ feat, const float* __restrict__ feat_aug,
    float* __restrict__ total, float* __restrict__ selfp, float* __restrict__ ap)
{
    __shared__ __align__(16) unsigned short As[128][72];
    __shared__ __align__(16) unsigned short Bs[128][72];
    __shared__ float ls_row[128];
    __shared__ float ls_col[128];

    const int tid  = threadIdx.x;
    const int lane = tid & 63;
    const int w    = tid >> 6;
    const int wm   = w >> 1;
    const int wn   = w & 1;
    const int lrow = lane & 15;
    const int quad = lane >> 4;

    const int tileM = blockIdx.x & 15;
    const int tileN = blockIdx.x >> 4;
    const int v     = blockIdx.y;
    const bool diag = (tileM >> 1) == (tileN >> 1);

    if (tid < 128) ls_row[tid] = 0.0f;
    else           ls_col[tid - 128] = 0.0f;

    const float* aBase = feat     + (size_t)v * 256;
    const float* bBase = feat_aug + (size_t)v * 256;

    f32x4 acc[4][4];
    #pragma unroll
    for (int i = 0; i < 4; ++i)
        #pragma unroll
        for (int j = 0; j < 4; ++j)
            acc[i][j] = (f32x4){0.f, 0.f, 0.f, 0.f};

    const int srow = tid >> 4;
    const int scol = (tid & 15) * 4;

    for (int s = 0; s < 4; ++s) {
        const int k0 = s * 64;
        if (s) __syncthreads();
        #pragma unroll
        for (int it = 0; it < 8; ++it) {
            const int row = it * 16 + srow;
            const float4 a4 = *(const float4*)(aBase + (size_t)(tileM * 128 + row) * 8192 + k0 + scol);
            const float4 b4 = *(const float4*)(bBase + (size_t)(tileN * 128 + row) * 8192 + k0 + scol);
            uint2 wa, wb;
            wa.x = (unsigned)f2bf(a4.x) | ((unsigned)f2bf(a4.y) << 16);
            wa.y = (unsigned)f2bf(a4.z) | ((unsigned)f2bf(a4.w) << 16);
            wb.x = (unsigned)f2bf(b4.x) | ((unsigned)f2bf(b4.y) << 16);
            wb.y = (unsigned)f2bf(b4.z) | ((unsigned)f2bf(b4.w) << 16);
            *(uint2*)&As[row][scol] = wa;
            *(uint2*)&Bs[row][scol] = wb;
        }
        __syncthreads();
        #pragma unroll
        for (int kk = 0; kk < 64; kk += 32) {
            bf16x8 af[4], bfr[4];
            #pragma unroll
            for (int t = 0; t < 4; ++t) {
                af[t]  = *(const bf16x8*)&As[wm * 64 + t * 16 + lrow][kk + quad * 8];
                bfr[t] = *(const bf16x8*)&Bs[wn * 64 + t * 16 + lrow][kk + quad * 8];
            }
            #pragma unroll
            for (int ti = 0; ti < 4; ++ti)
                #pragma unroll
                for (int tj = 0; tj < 4; ++tj)
                    acc[ti][tj] = __builtin_amdgcn_mfma_f32_16x16x32_bf16(
                        af[ti], bfr[tj], acc[ti][tj], 0, 0, 0);
        }
    }

    float colp[4] = {0.f, 0.f, 0.f, 0.f};
    #pragma unroll
    for (int ti = 0; ti < 4; ++ti) {
        #pragma unroll
        for (int r = 0; r < 4; ++r) {
            float e0 = __expf(acc[ti][0][r]);
            float e1 = __expf(acc[ti][1][r]);
            float e2 = __expf(acc[ti][2][r]);
            float e3 = __expf(acc[ti][3][r]);
            colp[0] += e0; colp[1] += e1; colp[2] += e2; colp[3] += e3;
            float rp = (e0 + e1) + (e2 + e3);
            rp += __shfl_xor(rp, 1);
            rp += __shfl_xor(rp, 2);
            rp += __shfl_xor(rp, 4);
            rp += __shfl_xor(rp, 8);
            if (lrow == 0)
                atomicAdd(&ls_row[wm * 64 + ti * 16 + quad * 4 + r], rp);
        }
    }
    if (diag) {
        #pragma unroll
        for (int tj = 0; tj < 4; ++tj) {
            float q = colp[tj];
            q += __shfl_xor(q, 16);
            q += __shfl_xor(q, 32);
            if (lane < 16)
                atomicAdd(&ls_col[wn * 64 + tj * 16 + lane], q);
        }
    }
    __syncthreads();
    if (tid < 128) {
        const float rs = ls_row[tid];
        const int rowg = tileM * 128 + tid;
        atomicAdd(&total[rowg], rs);
        if (diag) atomicAdd(&selfp[rowg], rs);
    } else if (diag) {
        const int t2 = tid - 128;
        atomicAdd(&ap[tileN * 128 + t2], ls_col[t2]);
    }
}

__global__ __launch_bounds__(256) void infonce_finalize(
    const float* __restrict__ total, const float* __restrict__ selfp,
    const float* __restrict__ ap, float* __restrict__ out)
{
    __shared__ float red[4];
    const int tid = threadIdx.x;
    float s = 0.f;
    for (int e = tid; e < 2048; e += 256) {
        const float an = total[e] - selfp[e];
        s += logf(an / ap[e]);
    }
    #pragma unroll
    for (int m = 32; m >= 1; m >>= 1) s += __shfl_xor(s, m);
    if ((tid & 63) == 0) red[tid >> 6] = s;
    __syncthreads();
    if (tid == 0) out[0] = (red[0] + red[1] + red[2] + red[3]) * (1.0f / 256.0f);
}

extern "C" void kernel_launch(void* const* d_in, const int* in_sizes, int n_in,
                              void* d_out, int out_size, void* d_ws, size_t ws_size,
                              hipStream_t stream) {
    const float* feat     = (const float*)d_in[0];
    const float* feat_aug = (const float*)d_in[1];
    float* total = (float*)d_ws;
    float* selfp = total + 2048;
    float* ap    = selfp + 2048;

    const size_t packBytes = (size_t)2048 * 8192;                  // per tensor, fp8
    const size_t need = 32768 + 2 * packBytes;
    if (ws_size >= need) {
        unsigned char* pA = (unsigned char*)d_ws + 32768;
        unsigned char* pB = pA + packBytes;
        infonce_repack_fp8<<<dim3(2048, 2), 256, 0, stream>>>(feat, feat_aug, pA, pB, total);
        infonce_main_nl<<<dim3(16, 32), 256, 0, stream>>>(pA, pB, total, selfp, ap);
    } else {
        (void)hipMemsetAsync(d_ws, 0, 3 * 2048 * sizeof(float), stream);
        infonce_main_slow<<<dim3(256, 32), 256, 0, stream>>>(feat, feat_aug, total, selfp, ap);
    }
    infonce_finalize<<<1, 256, 0, stream>>>(total, selfp, ap, (float*)d_out);
}

// Round 9
// 184.721 us; speedup vs baseline: 1.0575x; 1.0253x over previous
//
#include <hip/hip_runtime.h>
#include <hip/hip_bf16.h>

// Problem: B=8, T=256, V=32, D=256.
// Per-v GEMM: M=N=2048 (rows = i*T+q / j*T+k), K=256, then exp + 3 reductions.
// feature[B,T,V,D]: element (row, v, d) at feat[(row*32 + v)*256 + d].
// v9 = v5b main + A-repack eliminated (halve repack traffic):
//  - repack is B-only (67 MB read + 17 MB write, was 167 MB total): A is
//    consumed exactly once per block, so main stages fp32 A via coalesced
//    async16 into a 32 KB LDS buffer (4 chunks of 32 rows) and converts
//    in-LDS -> fp8 register fragments (x log2e, same op order as the old
//    repack => bit-identical numerics). v2's fusion failure used scattered
//    per-lane fp32 loads; this uses the proven coalesced global_load_lds.
//  - LDS 64 KB (Stage 32K + Bs 2x16K), 2 blocks/CU, counted-vmcnt N-sweep
//    byte-identical to v5b (185.3 us best). XCD decode reverted (v8 neutral).

typedef __attribute__((ext_vector_type(4))) float f32x4;
typedef __attribute__((ext_vector_type(4))) int   i32x4;
typedef __attribute__((ext_vector_type(8))) int   i32x8;
typedef __attribute__((ext_vector_type(8))) __bf16 bf16x8;   // fallback path

#if __has_builtin(__builtin_amdgcn_exp2f)
#define EXP2(x) __builtin_amdgcn_exp2f(x)
#else
#define EXP2(x) exp2f(x)
#endif

#define LOG2E 1.4426950408889634f

#define WAIT_VMCNT(N)                                              \
    do {                                                           \
        asm volatile("s_waitcnt vmcnt(" #N ")" ::: "memory");      \
        __builtin_amdgcn_sched_barrier(0);                         \
    } while (0)
#define WAIT_LGKM0                                                 \
    do {                                                           \
        asm volatile("s_waitcnt lgkmcnt(0)" ::: "memory");         \
        __builtin_amdgcn_sched_barrier(0);                         \
    } while (0)
#define BARRIER()                                                  \
    do {                                                           \
        __builtin_amdgcn_s_barrier();                              \
        __builtin_amdgcn_sched_barrier(0);                         \
    } while (0)

__device__ __forceinline__ unsigned short f2bf(float f) {
    unsigned u = __builtin_bit_cast(unsigned, f);
    u += 0x7FFFu + ((u >> 16) & 1u);   // RNE (no NaNs in data)
    return (unsigned short)(u >> 16);
}

template <bool HI>
__device__ __forceinline__ unsigned cvt2fp8(float a, float b, unsigned old) {
    return __builtin_amdgcn_cvt_pk_fp8_f32(a, b, old, HI);
}
__device__ __forceinline__ unsigned pack4fp8(float x, float y, float z, float w) {
    return cvt2fp8<true>(z, w, cvt2fp8<false>(x, y, 0u));
}

__device__ __forceinline__ void async16(const void* g, void* l) {
    __builtin_amdgcn_global_load_lds(
        (const __attribute__((address_space(1))) unsigned int*)g,
        (__attribute__((address_space(3))) unsigned int*)l,
        16, 0, 0);
}

__device__ __forceinline__ i32x8 cat8(i32x4 lo, i32x4 hi) {
    i32x8 r;
    r[0] = lo[0]; r[1] = lo[1]; r[2] = lo[2]; r[3] = lo[3];
    r[4] = hi[0]; r[5] = hi[1]; r[6] = hi[2]; r[7] = hi[3];
    return r;
}

// DPP row-sum over 16-lane rows; full sum lands in lane 15 of each row.
template <int CTRL>
__device__ __forceinline__ float dpp_add(float x) {
    int y = __builtin_amdgcn_update_dpp(0, __builtin_bit_cast(int, x),
                                        CTRL, 0xf, 0xf, true);
    return x + __builtin_bit_cast(float, y);
}
__device__ __forceinline__ float rowsum16(float x) {
    x = dpp_add<0x111>(x);   // row_shr:1
    x = dpp_add<0x112>(x);   // row_shr:2
    x = dpp_add<0x114>(x);   // row_shr:4
    x = dpp_add<0x118>(x);   // row_shr:8
    return x;
}

// ------------- repack: streaming fp32 -> fp8 e4m3, B tensor ONLY -------------
// grid (2048): lane-contiguous float4 loads + dword stores, grid-stride x8.
// Block 0 also zeroes the 3*2048 counter floats (replaces memset dispatch).
__global__ __launch_bounds__(256) void infonce_repack_fp8(
    const float* __restrict__ feat_aug, unsigned char* __restrict__ pB,
    float* __restrict__ counters)
{
    const int tid = threadIdx.x;
    if (blockIdx.x == 0) {
        #pragma unroll
        for (int k = 0; k < 24; ++k) counters[k * 256 + tid] = 0.f;
    }
    const unsigned g = blockIdx.x * 256u + (unsigned)tid;   // float4 lane slot
    #pragma unroll
    for (int it = 0; it < 8; ++it) {
        const unsigned idx = it * 524288u + g;              // float4 index
        const float4 f = *(const float4*)(feat_aug + (size_t)idx * 4);
        const unsigned p = pack4fp8(f.x, f.y, f.z, f.w);
        *(unsigned*)(pB + (size_t)idx * 4) = p;             // byte i = float i
    }
}

// ----- main: N-sweep MX-fp8 GEMM + exp + reductions, counted-vmcnt pipeline --
// block = (tileM 0..15, v 0..31). A: fp32 staged through a 32 KB LDS buffer
// (4 chunks of 32 rows), converted in-LDS to prescaled fp8 frags in regs.
// B: 2 x [64 rows][256 B] fp8 double buffer. 64 KB LDS, 2 blocks/CU.
__global__ __launch_bounds__(256, 2) void infonce_main_nl(
    const float* __restrict__ feat, const unsigned char* __restrict__ pB,
    float* __restrict__ total, float* __restrict__ selfp, float* __restrict__ ap)
{
    __shared__ __align__(16) unsigned char Stage[32 * 1024];   // fp32 A chunks
    __shared__ __align__(16) unsigned char Bs[2][64 * 256];
    // scratch aliases Stage after the final loop barrier (A frags in regs)
    float (*ls_row2)[128]  = (float (*)[128])(void*)Stage;
    float (*ls_self2)[128] = (float (*)[128])(void*)(Stage + 1024);

    const int tid  = threadIdx.x;
    const int lane = tid & 63;
    const int w    = tid >> 6;        // wave 0..3
    const int wm   = w >> 1;          // A rows half
    const int wn   = w & 1;           // B cols half (within 64-col tile)
    const int lrow = lane & 15;
    const int quad = lane >> 4;

    const int tileM = blockIdx.x;     // 0..15
    const int v     = blockIdx.y;     // 0..31
    const int nD0   = (tileM >> 1) * 4;   // first diagonal n-iter

    const size_t vOff = (size_t)v * 256;

    // ---- stage B tiles 0 and 1 first (in flight under A chunk 0) ----
    const size_t rowNbase = (size_t)(w * 16 + quad) * 8192 + vOff;
    #pragma unroll
    for (int nn = 0; nn < 2; ++nn) {
        const unsigned char* srcB = pB + rowNbase + (size_t)nn * 64 * 8192;
        #pragma unroll
        for (int i = 0; i < 4; ++i) {
            const int lg = (lrow ^ ((i * 4 + quad) & 15)) << 4;
            async16(srcB + (size_t)i * 4 * 8192 + lg,
                    &Bs[nn][(w * 16 + i * 4) * 256]);
        }
    }

    // ---- A tile: fp32 -> LDS (coalesced, swizzled) -> fp8 frags in regs ----
    // Chunk c holds tile rows [c*32, c*32+32); serves waves with wm == c>>1,
    // fragments t in {(c&1)*2, (c&1)*2+1}. LDS 16B-group p of local row rl
    // holds global group p ^ (rl & 15) (source pre-swizzle) so the fragment
    // read (group G at position G ^ lrow) is low-conflict.
    i32x8 af[2][4];   // [k-half][m-tile]
    #pragma unroll
    for (int c = 0; c < 4; ++c) {
        #pragma unroll
        for (int i = 0; i < 8; ++i) {
            const int rl = w * 8 + i;                     // chunk-local row
            const int gr = tileM * 128 + c * 32 + rl;     // global A row
            const int sg = lane ^ (rl & 15);              // source 16B group
            async16((const unsigned char*)feat +
                        ((size_t)gr * 8192 + vOff + (size_t)sg * 4) * 4,
                    &Stage[rl * 1024 + lane * 16]);
        }
        WAIT_VMCNT(0);     // chunk staged (c==0 also drains B0/B1: harmless)
        BARRIER();
        if ((c >> 1) == wm) {
            #pragma unroll
            for (int tt = 0; tt < 2; ++tt) {
                const int t  = (c & 1) * 2 + tt;          // compile-time
                const int rl = tt * 16 + lrow;            // local row
                #pragma unroll
                for (int h = 0; h < 2; ++h) {
                    i32x8 r;
                    #pragma unroll
                    for (int j = 0; j < 8; ++j) {
                        const int G = h * 32 + quad * 8 + j;   // global group
                        const float4 f = *(const float4*)
                            &Stage[rl * 1024 + ((G ^ lrow) * 16)];
                        r[j] = pack4fp8(f.x * LOG2E, f.y * LOG2E,
                                        f.z * LOG2E, f.w * LOG2E);
                    }
                    af[h][t] = r;
                }
            }
        }
        WAIT_LGKM0;        // my Stage reads done before next chunk overwrites
        BARRIER();
    }

    float rowp[4][4];   // row partials, all n
    float selfr[4][4];  // row partials, diagonal n only
    #pragma unroll
    for (int t = 0; t < 4; ++t)
        #pragma unroll
        for (int r = 0; r < 4; ++r) { rowp[t][r] = 0.f; selfr[t][r] = 0.f; }

    // Per-iteration body AFTER the vmcnt gate. Block-uniform branches only.
    auto iterBody = [&](const int n) {
        const int b = n & 1;
        BARRIER();                      // all waves: Bs[b] contents valid

        // ---- read ALL B fragments of this tile (8 x ds_read_b128) ----
        i32x8 bfr[2][2];                // [k-half][tj]
        #pragma unroll
        for (int h = 0; h < 2; ++h)
            #pragma unroll
            for (int tj = 0; tj < 2; ++tj) {
                const int rB = (wn * 32 + tj * 16 + lrow) * 256;
                const int g0 = ((h * 8 + quad * 2) ^ lrow) * 16;
                bfr[h][tj] = cat8(*(const i32x4*)&Bs[b][rB + g0],
                                  *(const i32x4*)&Bs[b][rB + (g0 ^ 16)]);
            }
        WAIT_LGKM0;                     // my reads of Bs[b] complete
        BARRIER();                      // everyone's reads done -> overwritable

        if (n < 30) {                   // stage tile n+2 into Bs[b]
            const unsigned char* src = pB + rowNbase + (size_t)(n + 2) * 64 * 8192;
            #pragma unroll
            for (int i = 0; i < 4; ++i) {
                const int lg = (lrow ^ ((i * 4 + quad) & 15)) << 4;
                async16(src + (size_t)i * 4 * 8192 + lg,
                        &Bs[b][(w * 16 + i * 4) * 256]);
            }
        }

        // ---- MFMA (regs only) ----
        f32x4 acc[4][2];
        #pragma unroll
        for (int t = 0; t < 4; ++t)
            #pragma unroll
            for (int tj = 0; tj < 2; ++tj)
                acc[t][tj] = (f32x4){0.f, 0.f, 0.f, 0.f};
        __builtin_amdgcn_s_setprio(1);
        #pragma unroll
        for (int h = 0; h < 2; ++h)
            #pragma unroll
            for (int ti = 0; ti < 4; ++ti)
                #pragma unroll
                for (int tj = 0; tj < 2; ++tj)
                    acc[ti][tj] = __builtin_amdgcn_mfma_scale_f32_16x16x128_f8f6f4(
                        af[h][ti], bfr[h][tj], acc[ti][tj],
                        0, 0, 0, 127, 0, 127);   // fp8/fp8, unit E8M0 scales
        __builtin_amdgcn_s_setprio(0);

        // ---- epilogue-accumulate: E = exp2(acc) (A prescaled by log2 e) ----
        const bool diagIter = (n >= nD0) && (n < nD0 + 4);
        float colp0 = 0.f, colp1 = 0.f;
        #pragma unroll
        for (int t = 0; t < 4; ++t)
            #pragma unroll
            for (int r = 0; r < 4; ++r) {
                float e0 = EXP2(acc[t][0][r]);
                float e1 = EXP2(acc[t][1][r]);
                rowp[t][r] += e0 + e1;
                if (diagIter) { selfr[t][r] += e0 + e1; colp0 += e0; colp1 += e1; }
            }
        if (diagIter) {   // col sums -> ap (wave-uniform branch, 4 of 32 iters)
            float q0 = colp0, q1 = colp1;
            q0 += __shfl_xor(q0, 16); q0 += __shfl_xor(q0, 32);
            q1 += __shfl_xor(q1, 16); q1 += __shfl_xor(q1, 32);
            if (lane < 16) {
                atomicAdd(&ap[n * 64 + wn * 32 + lane], q0);
                atomicAdd(&ap[n * 64 + wn * 32 + 16 + lane], q1);
            }
        }
        // no per-iter vmcnt drain: next iter's WAIT_VMCNT is the only gate
    };

    for (int n = 0; n < 31; ++n) {
        // Steady state: outstanding = tiles n (issued at n-2) + n+1 (at n-1);
        // wait(4) -> tile n landed. Iters 0/1: prologue already drained B0/B1.
        WAIT_VMCNT(4);
        iterBody(n);
    }
    WAIT_VMCNT(0);       // last tile: drain everything
    iterBody(31);

    // ---- final row reductions: DPP over the 16 cols held per lane-row ----
    #pragma unroll
    for (int t = 0; t < 4; ++t)
        #pragma unroll
        for (int r = 0; r < 4; ++r) {
            float rs = rowsum16(rowp[t][r]);
            float ss = rowsum16(selfr[t][r]);
            if (lrow == 15) {
                const int idx = wm * 64 + t * 16 + quad * 4 + r;
                ls_row2[wn][idx]  = rs;
                ls_self2[wn][idx] = ss;
            }
        }
    __syncthreads();
    if (tid < 128) {
        atomicAdd(&total[tileM * 128 + tid], ls_row2[0][tid] + ls_row2[1][tid]);
    } else {
        const int t2 = tid - 128;
        atomicAdd(&selfp[tileM * 128 + t2], ls_self2[0][t2] + ls_self2[1][t2]);
    }
}

// ---------------- fallback main (round-1 kernel, fp32 staging) ---------------
__global__ __launch_bounds__(256) void infonce_main_slow(
    const float* __restrict__ feat, const float* __restrict__ feat_aug,
    float* __restrict__ total, float* __restrict__ selfp, float* __restrict__ ap)
{
    __shared__ __align__(16) unsigned short As[128][72];
    __shared__ __align__(16) unsigned short Bs[128][72];
    __shared__ float ls_row[128];
    __shared__ float ls_col[128];

    const int tid  = threadIdx.x;
    const int lane = tid & 63;
    const int w    = tid >> 6;
    const int wm   = w >> 1;
    const int wn   = w & 1;
    const int lrow = lane & 15;
    const int quad = lane >> 4;

    const int tileM = blockIdx.x & 15;
    const int tileN = blockIdx.x >> 4;
    const int v     = blockIdx.y;
    const bool diag = (tileM >> 1) == (tileN >> 1);

    if (tid < 128) ls_row[tid] = 0.0f;
    else           ls_col[tid - 128] = 0.0f;

    const float* aBase = feat     + (size_t)v * 256;
    const float* bBase = feat_aug + (size_t)v * 256;

    f32x4 acc[4][4];
    #pragma unroll
    for (int i = 0; i < 4; ++i)
        #pragma unroll
        for (int j = 0; j < 4; ++j)
            acc[i][j] = (f32x4){0.f, 0.f, 0.f, 0.f};

    const int srow = tid >> 4;
    const int scol = (tid & 15) * 4;

    for (int s = 0; s < 4; ++s) {
        const int k0 = s * 64;
        if (s) __syncthreads();
        #pragma unroll
        for (int it = 0; it < 8; ++it) {
            const int row = it * 16 + srow;
            const float4 a4 = *(const float4*)(aBase + (size_t)(tileM * 128 + row) * 8192 + k0 + scol);
            const float4 b4 = *(const float4*)(bBase + (size_t)(tileN * 128 + row) * 8192 + k0 + scol);
            uint2 wa, wb;
            wa.x = (unsigned)f2bf(a4.x) | ((unsigned)f2bf(a4.y) << 16);
            wa.y = (unsigned)f2bf(a4.z) | ((unsigned)f2bf(a4.w) << 16);
            wb.x = (unsigned)f2bf(b4.x) | ((unsigned)f2bf(b4.y) << 16);
            wb.y = (unsigned)f2bf(b4.z) | ((unsigned)f2bf(b4.w) << 16);
            *(uint2*)&As[row][scol] = wa;
            *(uint2*)&Bs[row][scol] = wb;
        }
        __syncthreads();
        #pragma unroll
        for (int kk = 0; kk < 64; kk += 32) {
            bf16x8 af[4], bfr[4];
            #pragma unroll
            for (int t = 0; t < 4; ++t) {
                af[t]  = *(const bf16x8*)&As[wm * 64 + t * 16 + lrow][kk + quad * 8];
                bfr[t] = *(const bf16x8*)&Bs[wn * 64 + t * 16 + lrow][kk + quad * 8];
            }
            #pragma unroll
            for (int ti = 0; ti < 4; ++ti)
                #pragma unroll
                for (int tj = 0; tj < 4; ++tj)
                    acc[ti][tj] = __builtin_amdgcn_mfma_f32_16x16x32_bf16(
                        af[ti], bfr[tj], acc[ti][tj], 0, 0, 0);
        }
    }

    float colp[4] = {0.f, 0.f, 0.f, 0.f};
    #pragma unroll
    for (int ti = 0; ti < 4; ++ti) {
        #pragma unroll
        for (int r = 0; r < 4; ++r) {
            float e0 = __expf(acc[ti][0][r]);
            float e1 = __expf(acc[ti][1][r]);
            float e2 = __expf(acc[ti][2][r]);
            float e3 = __expf(acc[ti][3][r]);
            colp[0] += e0; colp[1] += e1; colp[2] += e2; colp[3] += e3;
            float rp = (e0 + e1) + (e2 + e3);
            rp += __shfl_xor(rp, 1);
            rp += __shfl_xor(rp, 2);
            rp += __shfl_xor(rp, 4);
            rp += __shfl_xor(rp, 8);
            if (lrow == 0)
                atomicAdd(&ls_row[wm * 64 + ti * 16 + quad * 4 + r], rp);
        }
    }
    if (diag) {
        #pragma unroll
        for (int tj = 0; tj < 4; ++tj) {
            float q = colp[tj];
            q += __shfl_xor(q, 16);
            q += __shfl_xor(q, 32);
            if (lane < 16)
                atomicAdd(&ls_col[wn * 64 + tj * 16 + lane], q);
        }
    }
    __syncthreads();
    if (tid < 128) {
        const float rs = ls_row[tid];
        const int rowg = tileM * 128 + tid;
        atomicAdd(&total[rowg], rs);
        if (diag) atomicAdd(&selfp[rowg], rs);
    } else if (diag) {
        const int t2 = tid - 128;
        atomicAdd(&ap[tileN * 128 + t2], ls_col[t2]);
    }
}

__global__ __launch_bounds__(256) void infonce_finalize(
    const float* __restrict__ total, const float* __restrict__ selfp,
    const float* __restrict__ ap, float* __restrict__ out)
{
    __shared__ float red[4];
    const int tid = threadIdx.x;
    float s = 0.f;
    for (int e = tid; e < 2048; e += 256) {
        const float an = total[e] - selfp[e];
        s += logf(an / ap[e]);
    }
    #pragma unroll
    for (int m = 32; m >= 1; m >>= 1) s += __shfl_xor(s, m);
    if ((tid & 63) == 0) red[tid >> 6] = s;
    __syncthreads();
    if (tid == 0) out[0] = (red[0] + red[1] + red[2] + red[3]) * (1.0f / 256.0f);
}

extern "C" void kernel_launch(void* const* d_in, const int* in_sizes, int n_in,
                              void* d_out, int out_size, void* d_ws, size_t ws_size,
                              hipStream_t stream) {
    const float* feat     = (const float*)d_in[0];
    const float* feat_aug = (const float*)d_in[1];
    float* total = (float*)d_ws;
    float* selfp = total + 2048;
    float* ap    = selfp + 2048;

    const size_t packBytes = (size_t)2048 * 8192;                  // B tensor, fp8
    const size_t need = 32768 + packBytes;
    if (ws_size >= need) {
        unsigned char* pB = (unsigned char*)d_ws + 32768;
        infonce_repack_fp8<<<dim3(2048), 256, 0, stream>>>(feat_aug, pB, total);
        infonce_main_nl<<<dim3(16, 32), 256, 0, stream>>>(feat, pB, total, selfp, ap);
    } else {
        (void)hipMemsetAsync(d_ws, 0, 3 * 2048 * sizeof(float), stream);
        infonce_main_slow<<<dim3(256, 32), 256, 0, stream>>>(feat, feat_aug, total, selfp, ap);
    }
    infonce_finalize<<<1, 256, 0, stream>>>(total, selfp, ap, (float*)d_out);
}